// Round 9
// baseline (203.524 us; speedup 1.0000x reference)
//
#include <hip/hip_runtime.h>
#include <math.h>

#define NN 768
#define DD 128
#define AA 312
#define HH 8
#define CEPS 1e-8f

typedef __attribute__((ext_vector_type(8))) short s8b;   // 8 x bf16
typedef __attribute__((ext_vector_type(4))) float f4v;   // MFMA C/D

__device__ __forceinline__ float wave_sum(float v) {
    #pragma unroll
    for (int o = 32; o; o >>= 1) v += __shfl_down(v, o, 64);
    return v;
}
__device__ __forceinline__ float wave_max(float v) {
    #pragma unroll
    for (int o = 32; o; o >>= 1) v = fmaxf(v, __shfl_down(v, o, 64));
    return v;
}
__device__ __forceinline__ unsigned short f2bf(float f) {
    unsigned u = __float_as_uint(f);
    u += 0x7FFFu + ((u >> 16) & 1u);
    return (unsigned short)(u >> 16);
}

// block-wide softmax (512 threads) over a 768-float LDS buffer, in place.
__device__ void block_softmax768(float* buf, int tid, float* red) {
    const int w = tid >> 6, lane = tid & 63;
    float v0 = buf[tid];
    float v1 = (tid < NN - 512) ? buf[tid + 512] : -3.4e38f;
    float m = wave_max(fmaxf(v0, v1));
    if (lane == 0) red[w] = m;
    __syncthreads();
    m = red[0];
    #pragma unroll
    for (int i = 1; i < 8; ++i) m = fmaxf(m, red[i]);
    float e0 = __expf(v0 - m);
    float e1 = (tid < NN - 512) ? __expf(v1 - m) : 0.f;
    float sw = wave_sum(e0 + e1);
    if (lane == 0) red[8 + w] = sw;
    __syncthreads();
    float s = 0.f;
    #pragma unroll
    for (int i = 0; i < 8; ++i) s += red[8 + i];
    const float inv = 1.f / s;
    buf[tid] = e0 * inv;
    if (tid < NN - 512) buf[tid + 512] = e1 * inv;
    __syncthreads();
}

// ---------------- K1: raw gram dots + diag inv-norms + W transposes ----------------
template <int COLS>
__device__ void gram_tile_raw(const float* __restrict__ A, float* __restrict__ sim,
                              float* __restrict__ invn, int i0, int j0, int tid, float* As,
                              float* Bs) {
    const int tx = tid & 15, ty = tid >> 4;
    const int lr = tid >> 3, lc4 = (tid & 7) * 4;
    float acc00 = 0.f, acc01 = 0.f, acc10 = 0.f, acc11 = 0.f;
    for (int kc = 0; kc < COLS; kc += 32) {
        float4 av, bv;
        if (kc + lc4 + 4 <= COLS) {
            av = *(const float4*)(A + (size_t)(i0 + lr) * COLS + kc + lc4);
            bv = *(const float4*)(A + (size_t)(j0 + lr) * COLS + kc + lc4);
        } else {
            float ta[4], tb[4];
            #pragma unroll
            for (int l = 0; l < 4; ++l) {
                int c = kc + lc4 + l;
                ta[l] = (c < COLS) ? A[(size_t)(i0 + lr) * COLS + c] : 0.f;
                tb[l] = (c < COLS) ? A[(size_t)(j0 + lr) * COLS + c] : 0.f;
            }
            av = make_float4(ta[0], ta[1], ta[2], ta[3]);
            bv = make_float4(tb[0], tb[1], tb[2], tb[3]);
        }
        __syncthreads();
        As[(lc4 + 0) * 34 + lr] = av.x; As[(lc4 + 1) * 34 + lr] = av.y;
        As[(lc4 + 2) * 34 + lr] = av.z; As[(lc4 + 3) * 34 + lr] = av.w;
        Bs[(lc4 + 0) * 34 + lr] = bv.x; Bs[(lc4 + 1) * 34 + lr] = bv.y;
        Bs[(lc4 + 2) * 34 + lr] = bv.z; Bs[(lc4 + 3) * 34 + lr] = bv.w;
        __syncthreads();
        #pragma unroll
        for (int k = 0; k < 32; ++k) {
            float2 aa = *(const float2*)&As[k * 34 + 2 * ty];
            float2 bb = *(const float2*)&Bs[k * 34 + 2 * tx];
            acc00 = fmaf(aa.x, bb.x, acc00);
            acc01 = fmaf(aa.x, bb.y, acc01);
            acc10 = fmaf(aa.y, bb.x, acc10);
            acc11 = fmaf(aa.y, bb.y, acc11);
        }
    }
    float* s0 = sim + (size_t)(i0 + 2 * ty) * NN + j0 + 2 * tx;
    float* s1 = s0 + NN;
    s0[0] = acc00; s0[1] = acc01;
    s1[0] = acc10; s1[1] = acc11;
    if (i0 == j0 && tx == ty) {  // diagonal elements: acc00=(i,i), acc11=(i+1,i+1)
        invn[i0 + 2 * tx] = 1.f / sqrtf(fmaxf(acc00, 1e-24f));
        invn[i0 + 2 * tx + 1] = 1.f / sqrtf(fmaxf(acc11, 1e-24f));
    }
}

__global__ __launch_bounds__(256) void gram_prep_kernel(
    const float* __restrict__ visual, const float* __restrict__ attribute,
    const float* __restrict__ Wvn, const float* __restrict__ Wsn, float* __restrict__ simv,
    float* __restrict__ sima, float* __restrict__ WvnT, float* __restrict__ WsnT,
    float* __restrict__ invnv, float* __restrict__ invna) {
    __shared__ __align__(16) float smem[2176];
    const int tid = threadIdx.x;
    const int task = blockIdx.x;
    if (task < 576) {
        gram_tile_raw<DD>(visual, simv, invnv, (task / 24) * 32, (task % 24) * 32, tid, smem,
                          smem + 1088);
    } else if (task < 1152) {
        const int rem = task - 576;
        gram_tile_raw<AA>(attribute, sima, invna, (rem / 24) * 32, (rem % 24) * 32, tid, smem,
                          smem + 1088);
    } else {
        const int u = task - 1152;
        const float* S = (u >= 16) ? Wsn : Wvn;
        float* Dt = (u >= 16) ? WsnT : WvnT;
        const int tile = u & 15;
        const int c0 = (tile & 3) * 32, r0 = (tile >> 2) * 32;
        const int tx = tid & 31, ty = tid >> 5;
        #pragma unroll
        for (int rr = ty; rr < 32; rr += 8)
            smem[rr * 33 + tx] = S[(size_t)(r0 + rr) * DD + c0 + tx];
        __syncthreads();
        #pragma unroll
        for (int rr = ty; rr < 32; rr += 8)
            Dt[(size_t)(c0 + rr) * DD + r0 + tx] = smem[tx * 33 + rr];
    }
}

// ---------------- K2/K4: node update (2 rows/block, 512 thr) ----------------
// EPSM: ep rows are raw gram dots -> scale by 10*invn_i*invn_k, softmax in-block.
// EXSM: same for ex; else ex is an already-softmaxed edge matrix (read direct).
template <bool EXSM>
__global__ __launch_bounds__(512) void node_kernel(
    const float* __restrict__ P, const float* __restrict__ EpRaw,
    const float* __restrict__ invnP, const float* __restrict__ Ex,
    const float* __restrict__ invnX, const float* __restrict__ WT, const float* __restrict__ b,
    const float* __restrict__ g, const float* __restrict__ beta, float* __restrict__ out,
    const float* __restrict__ W1e, short* __restrict__ outb, float* __restrict__ cvec) {
    __shared__ __align__(16) float ep[2][NN], ex[2][NN];
    __shared__ __align__(16) float pp[4][2][DD], xx[4][2][DD];
    __shared__ __align__(16) float qs[2][DD], tps[2][2][DD];
    __shared__ float red[16];
    const int i0 = blockIdx.x * 2;
    const int tid = threadIdx.x;
    const int s = (tid >> 7) & 3, d = tid & 127;
    const float cp0 = 10.f * invnP[i0], cp1 = 10.f * invnP[i0 + 1];
    const float cx0 = EXSM ? 10.f * invnX[i0] : 0.f;
    const float cx1 = EXSM ? 10.f * invnX[i0 + 1] : 0.f;
    #pragma unroll
    for (int r = 0; r < 2; ++r)
        for (int k = tid; k < NN; k += 512) {
            ep[r][k] = EpRaw[(size_t)(i0 + r) * NN + k] * (r ? cp1 : cp0) * invnP[k];
            float x = Ex[(size_t)(i0 + r) * NN + k];
            if (EXSM) x *= (r ? cx1 : cx0) * invnX[k];
            ex[r][k] = x;
        }
    __syncthreads();
    block_softmax768(ep[0], tid, red);
    block_softmax768(ep[1], tid, red);
    if (EXSM) {
        block_softmax768(ex[0], tid, red);
        block_softmax768(ex[1], tid, red);
    }
    float p0 = 0.f, x0 = 0.f, p1 = 0.f, x1 = 0.f;
    const int kb = s * 192;
    #pragma unroll 4
    for (int kk = 0; kk < 192; ++kk) {
        const int k = kb + kk;
        const float pv = P[(size_t)k * DD + d];
        p0 = fmaf(ep[0][k], pv, p0);
        x0 = fmaf(ex[0][k], pv, x0);
        p1 = fmaf(ep[1][k], pv, p1);
        x1 = fmaf(ex[1][k], pv, x1);
    }
    pp[s][0][d] = p0; xx[s][0][d] = x0;
    pp[s][1][d] = p1; xx[s][1][d] = x1;
    __syncthreads();
    const int rr = (tid >> 7) & 1;
    float preg = 0.f;
    if (tid < 256) {
        float p = pp[0][rr][d] + pp[1][rr][d] + pp[2][rr][d] + pp[3][rr][d];
        float x = xx[0][rr][d] + xx[1][rr][d] + xx[2][rr][d] + xx[3][rr][d];
        qs[rr][d] = p + x;
        preg = p;
    }
    __syncthreads();
    {
        const int sc = tid >> 8, rr2 = (tid >> 7) & 1;
        float t = (sc == 0) ? b[d] : 0.f;
        const int c0 = sc * 64;
        #pragma unroll 4
        for (int c = c0; c < c0 + 64; ++c) t = fmaf(qs[rr2][c], WT[(size_t)c * DD + d], t);
        tps[sc][rr2][d] = t;
    }
    __syncthreads();
    float tval = 0.f;
    if (tid < 256) tval = tps[0][rr][d] + tps[1][rr][d];
    float sm = wave_sum(tid < 256 ? tval : 0.f);
    if ((tid & 63) == 0) red[tid >> 6] = sm;
    __syncthreads();
    if (tid < 256) tval -= (red[2 * rr] + red[2 * rr + 1]) * (1.f / DD);
    float s2 = wave_sum(tid < 256 ? tval * tval : 0.f);
    if ((tid & 63) == 0) red[8 + (tid >> 6)] = s2;
    __syncthreads();
    if (tid < 256) {
        const float var = (red[8 + 2 * rr] + red[8 + 2 * rr + 1]) * (1.f / DD);
        const float ln = tval * rsqrtf(var + 1e-5f) * g[d] + beta[d];
        const float val = fmaxf(ln, 0.f) + preg;
        out[(size_t)(i0 + rr) * DD + d] = val;
        outb[(size_t)(i0 + rr) * DD + d] = (short)f2bf(val);
        qs[rr][d] = val;
    }
    __syncthreads();
    if (tid < 16) {
        const int row = tid >> 3, r = tid & 7;
        float ssum = 0.f;
        for (int k = 0; k < DD; ++k) {
            const float pv = qs[row][k];
            ssum = fmaf(W1e[r * DD + k], pv * pv, ssum);
        }
        cvec[(size_t)(i0 + row) * HH + r] = ssum;
    }
}

// ---------------- K3/K5: full-row edge update via MFMA, in-block softmax ----------------
// z[r](i,j)=ci[i][r]+cj[j][r]-2*G_r[i,j]+b1[r]; E[i][j]=softmax_j(tanh(IN-MLP)*(lastE+eps)*invtemp)
// Block = 2 rows, 512 thr (8 waves x 6 j-tiles of 16). lastE = softmax(raw*10*invn_i*invn_k).
__global__ __launch_bounds__(512) void edge_full_kernel(
    const float* __restrict__ PR, const short* __restrict__ PRb, const float* __restrict__ cvec,
    const float* __restrict__ lastRaw, const float* __restrict__ invnL,
    const float* __restrict__ W1, const float* __restrict__ b1, const float* __restrict__ W2,
    const float* __restrict__ b2, float invtemp, float* __restrict__ Eout) {
    const int i0 = blockIdx.x * 2;
    const int tid = threadIdx.x;
    const int lane = tid & 63, wave = tid >> 6;
    __shared__ __align__(16) float pi[2][DD];
    __shared__ __align__(16) float w1s[HH * DD];
    __shared__ __align__(16) short a_sw[4 * 64 * 8];
    __shared__ __align__(16) float lrow[2][NN];
    __shared__ __align__(16) float logits[2][NN];
    __shared__ float red[16];
    if (tid < 256) pi[tid >> 7][tid & 127] = PR[(size_t)(i0 + (tid >> 7)) * DD + (tid & 127)];
    else ((float4*)w1s)[tid - 256] = ((const float4*)W1)[tid - 256];
    const float cl0 = 10.f * invnL[i0], cl1 = 10.f * invnL[i0 + 1];
    #pragma unroll
    for (int r = 0; r < 2; ++r)
        for (int k = tid; k < NN; k += 512)
            lrow[r][k] = lastRaw[(size_t)(i0 + r) * NN + k] * (r ? cl1 : cl0) * invnL[k];
    __syncthreads();
    block_softmax768(lrow[0], tid, red);
    block_softmax768(lrow[1], tid, red);
    if (tid < 256) {  // build A fragments: m = il*8+r, k = t*32 + q*8 + e
        const int t = tid >> 6, m = lane & 15, q = lane >> 4;
        const int il = m >> 3, r = m & 7;
        const int kb = t * 32 + q * 8;
        s8b av;
        #pragma unroll
        for (int e = 0; e < 8; ++e)
            av[e] = (short)f2bf(pi[il][kb + e] * w1s[r * DD + kb + e]);
        *(s8b*)&a_sw[(t * 64 + lane) * 8] = av;
    }
    __syncthreads();
    s8b af[4];
    #pragma unroll
    for (int t = 0; t < 4; ++t) af[t] = *(const s8b*)&a_sw[(t * 64 + lane) * 8];
    const int q = lane >> 4, n = lane & 15;
    const int rbase = (q & 1) * 4;
    const int il = q >> 1;
    const float4 ci4 = *(const float4*)&cvec[(size_t)(i0 + il) * HH + rbase];
    const float4 b14 = *(const float4*)&b1[rbase];
    const float4 w24 = *(const float4*)&W2[rbase];
    const float b2s = b2[0];
    #pragma unroll
    for (int s = 0; s < 6; ++s) {
        const int j = (wave * 6 + s) * 16 + n;
        f4v acc = {0.f, 0.f, 0.f, 0.f};
        #pragma unroll
        for (int t = 0; t < 4; ++t) {
            const s8b bf = *(const s8b*)(PRb + (size_t)j * DD + t * 32 + q * 8);
            acc = __builtin_amdgcn_mfma_f32_16x16x32_bf16(af[t], bf, acc, 0, 0, 0);
        }
        const float4 cj = *(const float4*)&cvec[(size_t)j * HH + rbase];
        float z[4];
        z[0] = ci4.x + cj.x - 2.f * acc[0] + b14.x;
        z[1] = ci4.y + cj.y - 2.f * acc[1] + b14.y;
        z[2] = ci4.z + cj.z - 2.f * acc[2] + b14.z;
        z[3] = ci4.w + cj.w - 2.f * acc[3] + b14.w;
        float s1 = z[0] + z[1] + z[2] + z[3];
        float s2 = z[0] * z[0] + z[1] * z[1] + z[2] * z[2] + z[3] * z[3];
        s1 += __shfl_xor(s1, 16, 64);
        s2 += __shfl_xor(s2, 16, 64);
        const float mean = s1 * (1.f / HH);
        const float var = fmaxf(s2 * (1.f / HH) - mean * mean, 0.f);
        const float istd = rsqrtf(var + 1e-5f);
        float a2 = 0.f;
        a2 = fmaf(fmaxf((z[0] - mean) * istd, 0.f), w24.x, a2);
        a2 = fmaf(fmaxf((z[1] - mean) * istd, 0.f), w24.y, a2);
        a2 = fmaf(fmaxf((z[2] - mean) * istd, 0.f), w24.z, a2);
        a2 = fmaf(fmaxf((z[3] - mean) * istd, 0.f), w24.w, a2);
        a2 += __shfl_xor(a2, 16, 64);
        const float tv = tanhf(a2 + b2s);
        if ((q & 1) == 0) logits[il][j] = tv * (lrow[il][j] + CEPS) * invtemp;
    }
    __syncthreads();
    block_softmax768(logits[0], tid, red);
    block_softmax768(logits[1], tid, red);
    #pragma unroll
    for (int r = 0; r < 2; ++r)
        for (int k = tid; k < NN; k += 512)
            Eout[(size_t)(i0 + r) * NN + k] = logits[r][k];
}

extern "C" void kernel_launch(void* const* d_in, const int* in_sizes, int n_in, void* d_out,
                              int out_size, void* d_ws, size_t ws_size, hipStream_t stream) {
    const float* visual    = (const float*)d_in[0];
    const float* semantic  = (const float*)d_in[1];
    const float* attribute = (const float*)d_in[2];
    const float* Wvn  = (const float*)d_in[3];
    const float* bvn  = (const float*)d_in[4];
    const float* gvn  = (const float*)d_in[5];
    const float* betavn = (const float*)d_in[6];
    const float* Wve1 = (const float*)d_in[7];
    const float* bve1 = (const float*)d_in[8];
    const float* Wve2 = (const float*)d_in[9];
    const float* bve2 = (const float*)d_in[10];
    const float* Wsn  = (const float*)d_in[11];
    const float* bsn  = (const float*)d_in[12];
    const float* gsn  = (const float*)d_in[13];
    const float* betasn = (const float*)d_in[14];
    const float* Wse1 = (const float*)d_in[15];
    const float* bse1 = (const float*)d_in[16];
    const float* Wse2 = (const float*)d_in[17];
    const float* bse2 = (const float*)d_in[18];

    float* out = (float*)d_out;
    float* vp  = out;              // 768*128
    float* sp  = out + 98304;      // 768*128
    float* ve2 = out + 196608;     // 768*768
    float* se2 = out + 786432;     // 768*768

    float* ws    = (float*)d_ws;
    float* simv  = ws;             // 768*768 raw dots
    float* sima  = ws + 589824;    // 768*768 raw dots
    float* WvnT  = ws + 1179648;   // 128*128
    float* WsnT  = ws + 1196032;   // 128*128
    float* invnv = ws + 1212416;   // 768
    float* invna = ws + 1213184;   // 768
    float* cvec1 = ws + 1213952;   // 768*8
    float* cvec2 = ws + 1220096;   // 768*8
    short* vpb   = (short*)(ws + 1226240);  // 768*128 bf16
    short* spb   = (short*)(ws + 1275392);  // 768*128 bf16

    // chain: gram -> node1 -> edge1 -> node2 -> edge2  (5 links)
    gram_prep_kernel<<<1184, 256, 0, stream>>>(visual, attribute, Wvn, Wsn, simv, sima, WvnT,
                                               WsnT, invnv, invna);
    // node1: vp = f(visual, ep=softmax(simv·scale), ex=softmax(sima·scale))
    node_kernel<true><<<NN / 2, 512, 0, stream>>>(visual, simv, invnv, sima, invna, WvnT, bvn,
                                                  gvn, betavn, vp, Wve1, vpb, cvec1);
    // edge1: ve2 = softmax-row(edge-MLP(vp) * (ve+eps) / 10)
    edge_full_kernel<<<NN / 2, 512, 0, stream>>>(vp, vpb, cvec1, simv, invnv, Wve1, bve1, Wve2,
                                                 bve2, 0.1f, ve2);
    // node2: sp = f(semantic, ep=softmax(sima·scale), ex=ve2)
    node_kernel<false><<<NN / 2, 512, 0, stream>>>(semantic, sima, invna, ve2, nullptr, WsnT,
                                                   bsn, gsn, betasn, sp, Wse1, spb, cvec2);
    // edge2: se2
    edge_full_kernel<<<NN / 2, 512, 0, stream>>>(sp, spb, cvec2, sima, invna, Wse1, bse1, Wse2,
                                                 bse2, 0.1f, se2);
}

// Round 10
// 195.125 us; speedup vs baseline: 1.0430x; 1.0430x over previous
//
#include <hip/hip_runtime.h>
#include <math.h>

#define NN 768
#define DD 128
#define AA 312
#define HH 8
#define CEPS 1e-8f

typedef __attribute__((ext_vector_type(8))) short s8b;   // 8 x bf16
typedef __attribute__((ext_vector_type(4))) float f4v;   // MFMA C/D

__device__ __forceinline__ float wave_sum(float v) {
    #pragma unroll
    for (int o = 32; o; o >>= 1) v += __shfl_down(v, o, 64);
    return v;
}
__device__ __forceinline__ float wave_max(float v) {
    #pragma unroll
    for (int o = 32; o; o >>= 1) v = fmaxf(v, __shfl_down(v, o, 64));
    return v;
}
__device__ __forceinline__ unsigned short f2bf(float f) {
    unsigned u = __float_as_uint(f);
    u += 0x7FFFu + ((u >> 16) & 1u);
    return (unsigned short)(u >> 16);
}

// ---------------- K1: gram logits (inline row norms) + W transposes ----------------
template <int COLS>
__device__ void gram_tile(const float* __restrict__ A, float invtemp, float* __restrict__ sim,
                          int i0, int j0, int tid, float* As, float* Bs) {
    const int tx = tid & 15, ty = tid >> 4;
    const int lr = tid >> 3, lc4 = (tid & 7) * 4;
    float acc00 = 0.f, acc01 = 0.f, acc10 = 0.f, acc11 = 0.f;
    float si0 = 0.f, si1 = 0.f, sj0 = 0.f, sj1 = 0.f;
    for (int kc = 0; kc < COLS; kc += 32) {
        float4 av, bv;
        if (kc + lc4 + 4 <= COLS) {
            av = *(const float4*)(A + (size_t)(i0 + lr) * COLS + kc + lc4);
            bv = *(const float4*)(A + (size_t)(j0 + lr) * COLS + kc + lc4);
        } else {
            float ta[4], tb[4];
            #pragma unroll
            for (int l = 0; l < 4; ++l) {
                int c = kc + lc4 + l;
                ta[l] = (c < COLS) ? A[(size_t)(i0 + lr) * COLS + c] : 0.f;
                tb[l] = (c < COLS) ? A[(size_t)(j0 + lr) * COLS + c] : 0.f;
            }
            av = make_float4(ta[0], ta[1], ta[2], ta[3]);
            bv = make_float4(tb[0], tb[1], tb[2], tb[3]);
        }
        __syncthreads();
        As[(lc4 + 0) * 34 + lr] = av.x; As[(lc4 + 1) * 34 + lr] = av.y;
        As[(lc4 + 2) * 34 + lr] = av.z; As[(lc4 + 3) * 34 + lr] = av.w;
        Bs[(lc4 + 0) * 34 + lr] = bv.x; Bs[(lc4 + 1) * 34 + lr] = bv.y;
        Bs[(lc4 + 2) * 34 + lr] = bv.z; Bs[(lc4 + 3) * 34 + lr] = bv.w;
        __syncthreads();
        #pragma unroll
        for (int k = 0; k < 32; ++k) {
            float2 aa = *(const float2*)&As[k * 34 + 2 * ty];
            float2 bb = *(const float2*)&Bs[k * 34 + 2 * tx];
            acc00 = fmaf(aa.x, bb.x, acc00);
            acc01 = fmaf(aa.x, bb.y, acc01);
            acc10 = fmaf(aa.y, bb.x, acc10);
            acc11 = fmaf(aa.y, bb.y, acc11);
            si0 = fmaf(aa.x, aa.x, si0);
            si1 = fmaf(aa.y, aa.y, si1);
            sj0 = fmaf(bb.x, bb.x, sj0);
            sj1 = fmaf(bb.y, bb.y, sj1);
        }
    }
    const float ni0 = sqrtf(si0), ni1 = sqrtf(si1);
    const float nj0 = sqrtf(sj0), nj1 = sqrtf(sj1);
    float* s0 = sim + (size_t)(i0 + 2 * ty) * NN + j0 + 2 * tx;
    float* s1 = s0 + NN;
    s0[0] = acc00 / fmaxf(ni0 * nj0, CEPS) * invtemp;
    s0[1] = acc01 / fmaxf(ni0 * nj1, CEPS) * invtemp;
    s1[0] = acc10 / fmaxf(ni1 * nj0, CEPS) * invtemp;
    s1[1] = acc11 / fmaxf(ni1 * nj1, CEPS) * invtemp;
}

__global__ __launch_bounds__(256) void gram_prep_kernel(
    const float* __restrict__ visual, const float* __restrict__ attribute,
    const float* __restrict__ Wvn, const float* __restrict__ Wsn, float* __restrict__ simv,
    float* __restrict__ sima, float* __restrict__ WvnT, float* __restrict__ WsnT) {
    __shared__ __align__(16) float smem[2176];
    const int tid = threadIdx.x;
    const int task = blockIdx.x;
    if (task < 576) {
        gram_tile<DD>(visual, 10.f, simv, (task / 24) * 32, (task % 24) * 32, tid, smem,
                      smem + 1088);
    } else if (task < 1152) {
        const int rem = task - 576;
        gram_tile<AA>(attribute, 10.f, sima, (rem / 24) * 32, (rem % 24) * 32, tid, smem,
                      smem + 1088);
    } else {
        const int u = task - 1152;
        const float* S = (u >= 16) ? Wsn : Wvn;
        float* Dt = (u >= 16) ? WsnT : WvnT;
        const int tile = u & 15;
        const int c0 = (tile & 3) * 32, r0 = (tile >> 2) * 32;
        const int tx = tid & 31, ty = tid >> 5;
        #pragma unroll
        for (int rr = ty; rr < 32; rr += 8)
            smem[rr * 33 + tx] = S[(size_t)(r0 + rr) * DD + c0 + tx];
        __syncthreads();
        #pragma unroll
        for (int rr = ty; rr < 32; rr += 8)
            Dt[(size_t)(c0 + rr) * DD + r0 + tx] = smem[tx * 33 + rr];
    }
}

// ---------------- row softmax: global -> global (256 thr, 3 cols/thr) ----------------
__device__ void softmax_row_g(const float* __restrict__ vr, float* __restrict__ dst, int tid,
                              float* red) {
    float v0 = vr[tid], v1 = vr[tid + 256], v2 = vr[tid + 512];
    float m = wave_max(fmaxf(fmaxf(v0, v1), v2));
    if ((tid & 63) == 0) red[tid >> 6] = m;
    __syncthreads();
    m = fmaxf(fmaxf(red[0], red[1]), fmaxf(red[2], red[3]));
    float e0 = __expf(v0 - m), e1 = __expf(v1 - m), e2 = __expf(v2 - m);
    float sw = wave_sum(e0 + e1 + e2);
    if ((tid & 63) == 0) red[4 + (tid >> 6)] = sw;
    __syncthreads();
    const float s = red[4] + red[5] + red[6] + red[7];
    const float inv = 1.f / s;
    dst[tid] = e0 * inv;
    dst[tid + 256] = e1 * inv;
    dst[tid + 512] = e2 * inv;
}

// K2: softmax(simv)->ve, softmax(sima)->se (1536 blocks)
__global__ __launch_bounds__(256) void softmax_all_kernel(const float* __restrict__ simv,
                                                          const float* __restrict__ sima,
                                                          float* __restrict__ ve,
                                                          float* __restrict__ se) {
    __shared__ float red[8];
    const int task = blockIdx.x;
    const float* src = (task < NN) ? simv + (size_t)task * NN : sima + (size_t)(task - NN) * NN;
    float* dst = (task < NN) ? ve + (size_t)task * NN : se + (size_t)(task - NN) * NN;
    softmax_row_g(src, dst, threadIdx.x, red);
}

// K7: softmax(L)->out (768 blocks)
__global__ __launch_bounds__(256) void softmax_out_kernel(const float* __restrict__ L,
                                                          float* __restrict__ dst) {
    __shared__ float red[8];
    const int i = blockIdx.x;
    softmax_row_g(L + (size_t)i * NN, dst + (size_t)i * NN, threadIdx.x, red);
}

// block-wide softmax (512 threads) over a 768-float LDS buffer, in place.
__device__ void block_softmax768(float* buf, int tid, float* red) {
    const int w = tid >> 6, lane = tid & 63;
    float v0 = buf[tid];
    float v1 = (tid < NN - 512) ? buf[tid + 512] : -3.4e38f;
    float m = wave_max(fmaxf(v0, v1));
    if (lane == 0) red[w] = m;
    __syncthreads();
    m = red[0];
    #pragma unroll
    for (int i = 1; i < 8; ++i) m = fmaxf(m, red[i]);
    float e0 = __expf(v0 - m);
    float e1 = (tid < NN - 512) ? __expf(v1 - m) : 0.f;
    float sw = wave_sum(e0 + e1);
    if (lane == 0) red[8 + w] = sw;
    __syncthreads();
    float s = 0.f;
    #pragma unroll
    for (int i = 0; i < 8; ++i) s += red[8 + i];
    const float inv = 1.f / s;
    buf[tid] = e0 * inv;
    if (tid < NN - 512) buf[tid + 512] = e1 * inv;
    __syncthreads();
}

// ---------------- K3/K5: node update (2 rows/block, 512 thr) ----------------
// p = ep@P, x = ex@P, out = relu(LN((p+x)@WT+b)*g+beta) + p ; also bf16 row + cvec for next edge.
// EXSM: ex rows come from logits L (softmax applied here) and are also written to exOut (ve2).
template <bool EXSM>
__global__ __launch_bounds__(512) void node_kernel(
    const float* __restrict__ P, const float* __restrict__ Ep, const float* __restrict__ ExOrL,
    const float* __restrict__ WT, const float* __restrict__ b, const float* __restrict__ g,
    const float* __restrict__ beta, float* __restrict__ out, const float* __restrict__ W1e,
    short* __restrict__ outb, float* __restrict__ cvec, float* __restrict__ exOut) {
    __shared__ __align__(16) float ep[2][NN], ex[2][NN];
    __shared__ __align__(16) float pp[4][2][DD], xx[4][2][DD];
    __shared__ __align__(16) float qs[2][DD], tps[2][2][DD];
    __shared__ float red[16];
    const int i0 = blockIdx.x * 2;
    const int tid = threadIdx.x;
    const int s = (tid >> 7) & 3, d = tid & 127;
    #pragma unroll
    for (int r = 0; r < 2; ++r)
        for (int k = tid; k < NN; k += 512) {
            ep[r][k] = Ep[(size_t)(i0 + r) * NN + k];
            ex[r][k] = ExOrL[(size_t)(i0 + r) * NN + k];
        }
    __syncthreads();
    if (EXSM) {
        block_softmax768(ex[0], tid, red);
        block_softmax768(ex[1], tid, red);
        #pragma unroll
        for (int r = 0; r < 2; ++r)
            for (int k = tid; k < NN; k += 512) exOut[(size_t)(i0 + r) * NN + k] = ex[r][k];
    }
    float p0 = 0.f, x0 = 0.f, p1 = 0.f, x1 = 0.f;
    const int kb = s * 192;
    #pragma unroll 4
    for (int kk = 0; kk < 192; ++kk) {
        const int k = kb + kk;
        const float pv = P[(size_t)k * DD + d];
        p0 = fmaf(ep[0][k], pv, p0);
        x0 = fmaf(ex[0][k], pv, x0);
        p1 = fmaf(ep[1][k], pv, p1);
        x1 = fmaf(ex[1][k], pv, x1);
    }
    pp[s][0][d] = p0; xx[s][0][d] = x0;
    pp[s][1][d] = p1; xx[s][1][d] = x1;
    __syncthreads();
    const int rr = (tid >> 7) & 1;
    float preg = 0.f;
    if (tid < 256) {
        float p = pp[0][rr][d] + pp[1][rr][d] + pp[2][rr][d] + pp[3][rr][d];
        float x = xx[0][rr][d] + xx[1][rr][d] + xx[2][rr][d] + xx[3][rr][d];
        qs[rr][d] = p + x;
        preg = p;
    }
    __syncthreads();
    {
        const int sc = tid >> 8, rr2 = (tid >> 7) & 1;
        float t = (sc == 0) ? b[d] : 0.f;
        const int c0 = sc * 64;
        #pragma unroll 4
        for (int c = c0; c < c0 + 64; ++c) t = fmaf(qs[rr2][c], WT[(size_t)c * DD + d], t);
        tps[sc][rr2][d] = t;
    }
    __syncthreads();
    float tval = 0.f;
    if (tid < 256) tval = tps[0][rr][d] + tps[1][rr][d];
    float sm = wave_sum(tid < 256 ? tval : 0.f);
    if ((tid & 63) == 0) red[tid >> 6] = sm;
    __syncthreads();
    if (tid < 256) tval -= (red[2 * rr] + red[2 * rr + 1]) * (1.f / DD);
    float s2 = wave_sum(tid < 256 ? tval * tval : 0.f);
    if ((tid & 63) == 0) red[8 + (tid >> 6)] = s2;
    __syncthreads();
    if (tid < 256) {
        const float var = (red[8 + 2 * rr] + red[8 + 2 * rr + 1]) * (1.f / DD);
        const float ln = tval * rsqrtf(var + 1e-5f) * g[d] + beta[d];
        const float val = fmaxf(ln, 0.f) + preg;
        out[(size_t)(i0 + rr) * DD + d] = val;
        outb[(size_t)(i0 + rr) * DD + d] = (short)f2bf(val);
        qs[rr][d] = val;
    }
    __syncthreads();
    if (tid < 16) {
        const int row = tid >> 3, r = tid & 7;
        float ssum = 0.f;
        for (int k = 0; k < DD; ++k) {
            const float pv = qs[row][k];
            ssum = fmaf(W1e[r * DD + k], pv * pv, ssum);
        }
        cvec[(size_t)(i0 + row) * HH + r] = ssum;
    }
}

// ---------------- K4/K6: edge logits via MFMA (GEMM-shaped grid) ----------------
// z[r](i,j) = ci[i][r]+cj[j][r]-2*G_r[i,j]+b1[r]; L[i][j]=tanh(IN-MLP)*(Elast[i][j]+eps)*invtemp.
// grid: (NN/2)*3 blocks; block = i-pair (bp) x 256-wide j-chunk; 4 waves x 4 j-tiles each.
__global__ __launch_bounds__(256) void edge_gemm_kernel(
    const float* __restrict__ PR, const short* __restrict__ PRb, const float* __restrict__ cvec,
    const float* __restrict__ Elast, const float* __restrict__ W1, const float* __restrict__ b1,
    const float* __restrict__ W2, const float* __restrict__ b2, float invtemp,
    float* __restrict__ Lout) {
    const int bp = blockIdx.x / 3;
    const int i0 = bp * 2;
    const int jbase = (blockIdx.x % 3) * 256;
    const int tid = threadIdx.x;
    const int lane = tid & 63, wave = tid >> 6;
    __shared__ __align__(16) float pi[2][DD];
    __shared__ __align__(16) float w1s[HH * DD];
    __shared__ __align__(16) short a_sw[4 * 64 * 8];
    if (tid < 256) pi[tid >> 7][tid & 127] = PR[(size_t)(i0 + (tid >> 7)) * DD + (tid & 127)];
    ((float4*)w1s)[tid] = ((const float4*)W1)[tid];
    __syncthreads();
    {   // A fragments: m = il*8+r (il = i-row, r = hidden), k = t*32 + q*8 + e
        const int t = tid >> 6, m = lane & 15, q = lane >> 4;
        const int il = m >> 3, r = m & 7;
        const int kb = t * 32 + q * 8;
        s8b av;
        #pragma unroll
        for (int e = 0; e < 8; ++e)
            av[e] = (short)f2bf(pi[il][kb + e] * w1s[r * DD + kb + e]);
        *(s8b*)&a_sw[(t * 64 + lane) * 8] = av;
    }
    __syncthreads();
    s8b af[4];
    #pragma unroll
    for (int t = 0; t < 4; ++t) af[t] = *(const s8b*)&a_sw[(t * 64 + lane) * 8];
    const int q = lane >> 4, n = lane & 15;
    const int rbase = (q & 1) * 4;
    const int il = q >> 1;
    const float4 ci4 = *(const float4*)&cvec[(size_t)(i0 + il) * HH + rbase];
    const float4 b14 = *(const float4*)&b1[rbase];
    const float4 w24 = *(const float4*)&W2[rbase];
    const float b2s = b2[0];
    #pragma unroll
    for (int s = 0; s < 4; ++s) {
        const int j = jbase + (wave * 4 + s) * 16 + n;
        f4v acc = {0.f, 0.f, 0.f, 0.f};
        #pragma unroll
        for (int t = 0; t < 4; ++t) {
            const s8b bf = *(const s8b*)(PRb + (size_t)j * DD + t * 32 + q * 8);
            acc = __builtin_amdgcn_mfma_f32_16x16x32_bf16(af[t], bf, acc, 0, 0, 0);
        }
        const float4 cj = *(const float4*)&cvec[(size_t)j * HH + rbase];
        float z[4];
        z[0] = ci4.x + cj.x - 2.f * acc[0] + b14.x;
        z[1] = ci4.y + cj.y - 2.f * acc[1] + b14.y;
        z[2] = ci4.z + cj.z - 2.f * acc[2] + b14.z;
        z[3] = ci4.w + cj.w - 2.f * acc[3] + b14.w;
        float s1 = z[0] + z[1] + z[2] + z[3];
        float s2 = z[0] * z[0] + z[1] * z[1] + z[2] * z[2] + z[3] * z[3];
        s1 += __shfl_xor(s1, 16, 64);
        s2 += __shfl_xor(s2, 16, 64);
        const float mean = s1 * (1.f / HH);
        const float var = fmaxf(s2 * (1.f / HH) - mean * mean, 0.f);
        const float istd = rsqrtf(var + 1e-5f);
        float a2 = 0.f;
        a2 = fmaf(fmaxf((z[0] - mean) * istd, 0.f), w24.x, a2);
        a2 = fmaf(fmaxf((z[1] - mean) * istd, 0.f), w24.y, a2);
        a2 = fmaf(fmaxf((z[2] - mean) * istd, 0.f), w24.z, a2);
        a2 = fmaf(fmaxf((z[3] - mean) * istd, 0.f), w24.w, a2);
        a2 += __shfl_xor(a2, 16, 64);
        const float tv = tanhf(a2 + b2s);
        const float lv = Elast[(size_t)(i0 + il) * NN + j];
        if ((q & 1) == 0) Lout[(size_t)(i0 + il) * NN + j] = tv * (lv + CEPS) * invtemp;
    }
}

extern "C" void kernel_launch(void* const* d_in, const int* in_sizes, int n_in, void* d_out,
                              int out_size, void* d_ws, size_t ws_size, hipStream_t stream) {
    const float* visual    = (const float*)d_in[0];
    const float* semantic  = (const float*)d_in[1];
    const float* attribute = (const float*)d_in[2];
    const float* Wvn  = (const float*)d_in[3];
    const float* bvn  = (const float*)d_in[4];
    const float* gvn  = (const float*)d_in[5];
    const float* betavn = (const float*)d_in[6];
    const float* Wve1 = (const float*)d_in[7];
    const float* bve1 = (const float*)d_in[8];
    const float* Wve2 = (const float*)d_in[9];
    const float* bve2 = (const float*)d_in[10];
    const float* Wsn  = (const float*)d_in[11];
    const float* bsn  = (const float*)d_in[12];
    const float* gsn  = (const float*)d_in[13];
    const float* betasn = (const float*)d_in[14];
    const float* Wse1 = (const float*)d_in[15];
    const float* bse1 = (const float*)d_in[16];
    const float* Wse2 = (const float*)d_in[17];
    const float* bse2 = (const float*)d_in[18];

    float* out = (float*)d_out;
    float* vp  = out;              // 768*128
    float* sp  = out + 98304;      // 768*128
    float* ve2 = out + 196608;     // 768*768
    float* se2 = out + 786432;     // 768*768

    float* ws    = (float*)d_ws;
    float* simv  = ws;             // 768*768
    float* sima  = ws + 589824;
    float* ve    = ws + 1179648;   // softmax(simv)
    float* se    = ws + 1769472;   // softmax(sima)
    float* L     = ws + 2359296;   // raw edge logits (reused for both edges)
    float* WvnT  = ws + 2949120;   // 128*128
    float* WsnT  = ws + 2965504;
    float* cvec1 = ws + 2981888;   // 768*8
    float* cvec2 = ws + 2988032;
    short* vpb   = (short*)(ws + 2994176);  // 768*128 bf16
    short* spb   = (short*)(ws + 3043328);

    gram_prep_kernel<<<1184, 256, 0, stream>>>(visual, attribute, Wvn, Wsn, simv, sima, WvnT,
                                               WsnT);
    softmax_all_kernel<<<1536, 256, 0, stream>>>(simv, sima, ve, se);
    // node1: vp = f(visual, ep=ve, ex=se)
    node_kernel<false><<<NN / 2, 512, 0, stream>>>(visual, ve, se, WvnT, bvn, gvn, betavn, vp,
                                                   Wve1, vpb, cvec1, nullptr);
    // edge1 logits
    edge_gemm_kernel<<<(NN / 2) * 3, 256, 0, stream>>>(vp, vpb, cvec1, ve, Wve1, bve1, Wve2,
                                                       bve2, 0.1f, L);
    // node2: sp = f(semantic, ep=se, ex=softmax(L)->ve2)
    node_kernel<true><<<NN / 2, 512, 0, stream>>>(semantic, se, L, WsnT, bsn, gsn, betasn, sp,
                                                  Wse1, spb, cvec2, ve2);
    // edge2 logits
    edge_gemm_kernel<<<(NN / 2) * 3, 256, 0, stream>>>(sp, spb, cvec2, se, Wse1, bse1, Wse2,
                                                       bse2, 0.1f, L);
    softmax_out_kernel<<<NN, 256, 0, stream>>>(L, se2);
}